// Round 10
// baseline (28.914 us; speedup 1.0000x reference)
//
#include <hip/hip_runtime.h>
#include <math.h>

// Problem constants (from reference setup_inputs)
#define BB 16
#define QQ 900
#define NC 92
#define NCP 96          // padded class count (classes 92..95 have prob 0)
#define TT 1600
#define BQ (BB * QQ)    // 14400

// ---------------------------------------------------------------------------
// R10: R6/R9 per-wave structure, repacked into 1-WAVE BLOCKS for load
// balance.
//   grid = (BQ/2 = 7200, 1), block = 64 = 1 wave. 7200/256 = 28.1
//   blocks/CU, ALL co-resident (32 wave slots) -> tail imbalance 3.6%
//   instead of 14% with 1800 4-wave blocks (8/7 round-up).
//   Wave owns 2 rows; 64 lanes sweep all 1600 targets (25 iters).
//   LDS: normalized probs transposed pg[class][2] (768 B); one
//   ds_read_b64 fetches both rows' probs (validated R9, neutral-cost).
//   Wave-synchronous: no __syncthreads anywhere.
// ---------------------------------------------------------------------------
#define RT 2        // rows per wave
#define NK 25       // 25 x 64 targets = 1600

__global__ __launch_bounds__(64)
void k_cost(const float* __restrict__ logits,
            const float* __restrict__ boxes,       // [BQ,4] cxcywh
            const int* __restrict__ tids,          // [TT] int32
            const float* __restrict__ tbox,        // [TT,4] cxcywh
            float* __restrict__ out) {
    __shared__ float pg[NCP][RT];                  // [class][row], 768 B

    const int row0 = blockIdx.x * RT;
    const int tl   = threadIdx.x;                  // 0..63

    // ---- stage unnormalized exp(logit), transposed; classes 92..95 = 0 ----
    #pragma unroll
    for (int it = 0; it < 3; ++it) {               // 3 x 64 = 192 = 2*96
        int idx = it * 64 + tl;
        int r = idx / NCP, c = idx - r * NCP;
        float v = 0.0f;
        if (c < NC) v = __expf(logits[(row0 + r) * NC + c]);
        pg[c][r] = v;
    }
    __builtin_amdgcn_s_waitcnt(0);                 // LDS writes visible (same wave)

    // ---- normalize in place: half-wave per row, 3 classes per lane ----
    {
        const int lr = tl >> 5;                    // 0..1  (row)
        const int ls = tl & 31;                    // 0..31 (3*31+2 = 95)
        float a = pg[ls * 3][lr];
        float b = pg[ls * 3 + 1][lr];
        float d = pg[ls * 3 + 2][lr];
        float s = a + b + d;
        s += __shfl_xor(s, 1);
        s += __shfl_xor(s, 2);
        s += __shfl_xor(s, 4);
        s += __shfl_xor(s, 8);
        s += __shfl_xor(s, 16);                    // sum within the 32-half
        float rinv = __builtin_amdgcn_rcpf(s);
        pg[ls * 3][lr]     = a * rinv;
        pg[ls * 3 + 1][lr] = b * rinv;
        pg[ls * 3 + 2][lr] = d * rinv;
    }

    // ---- register-blocked row box data ----
    float rcx[RT], rcy[RT], rw[RT], rh[RT];
    float rx0[RT], ry0[RT], rx1[RT], ry1[RT], rar[RT];
    #pragma unroll
    for (int j = 0; j < RT; ++j) {
        float4 bb = ((const float4*)boxes)[row0 + j];
        rcx[j] = bb.x; rcy[j] = bb.y; rw[j] = bb.z; rh[j] = bb.w;
        rx0[j] = bb.x - 0.5f * bb.z; ry0[j] = bb.y - 0.5f * bb.w;
        rx1[j] = bb.x + 0.5f * bb.z; ry1[j] = bb.y + 0.5f * bb.w;
        rar[j] = bb.z * bb.w;
    }
    __builtin_amdgcn_s_waitcnt(0);                 // normalized probs visible

    // ---- main loop: 25 x 64 targets, prefetch, plain stores ----
    float* o0 = out + row0 * TT + tl;
    float4 tb = ((const float4*)tbox)[tl];
    int    id = tids[tl];
    #pragma unroll 5
    for (int k = 0; k < NK; ++k) {
        float4 tbn; int idn;
        if (k + 1 < NK) {
            tbn = ((const float4*)tbox)[(k + 1) * 64 + tl];
            idn = tids[(k + 1) * 64 + tl];
        }
        // ONE b64 gather: probs for both rows
        float2 pp = *(const float2*)&pg[id][0];
        float tx0 = tb.x - 0.5f * tb.z, ty0 = tb.y - 0.5f * tb.w;
        float tx1 = tb.x + 0.5f * tb.z, ty1 = tb.y + 0.5f * tb.w;
        float tar = tb.z * tb.w;
        #pragma unroll
        for (int j = 0; j < RT; ++j) {
            // L1 cdist in cxcywh space
            float l1 = fabsf(rcx[j] - tb.x) + fabsf(rcy[j] - tb.y)
                     + fabsf(rw[j]  - tb.z) + fabsf(rh[j]  - tb.w);
            // unclamped intersection extents
            float iwu = fminf(rx1[j], tx1) - fmaxf(rx0[j], tx0);
            float ihu = fminf(ry1[j], ty1) - fmaxf(ry0[j], ty0);
            float inter = fmaxf(iwu, 0.0f) * fmaxf(ihu, 0.0f);
            float uni = rar[j] + tar - inter;
            // enclosing box via min+max identity (always non-negative)
            float ew = (rw[j] + tb.z) - iwu;
            float eh = (rh[j] + tb.w) - ihu;
            float ea = ew * eh;
            // giou = (ea*(inter-uni) + uni^2) / (uni*ea), single rcp
            float num = fmaf(ea, inter - uni, uni * uni);
            float rden = __builtin_amdgcn_rcpf(uni * ea);
            // C = 5*l1 - p - 2*giou
            float p = (j == 0) ? pp.x : pp.y;
            float c = fmaf(5.0f, l1, -p);
            c = fmaf(-2.0f * num, rden, c);
            o0[j * TT + k * 64] = c;
        }
        tb = tbn; id = idn;
    }
}

// ---------------------------------------------------------------------------
extern "C" void kernel_launch(void* const* d_in, const int* in_sizes, int n_in,
                              void* d_out, int out_size, void* d_ws, size_t ws_size,
                              hipStream_t stream) {
    const float* logits = (const float*)d_in[0];   // [16,900,92] f32
    const float* boxes  = (const float*)d_in[1];   // [16,900,4]  f32
    const int*   tids   = (const int*)  d_in[2];   // [1600] int32
    const float* tbox   = (const float*)d_in[3];   // [1600,4] f32
    float* out = (float*)d_out;

    k_cost<<<dim3(BQ / RT, 1), 64, 0, stream>>>(
        logits, boxes, tids, tbox, out);
}

// Round 12
// 27.086 us; speedup vs baseline: 1.0675x; 1.0675x over previous
//
#include <hip/hip_runtime.h>
#include <math.h>

// Problem constants (from reference setup_inputs)
#define BB 16
#define QQ 900
#define NC 92
#define NCP 96          // padded LDS row
#define TT 1600
#define BQ (BB * QQ)    // 14400

// ---------------------------------------------------------------------------
// R12: R6 structure + CORRECTED half-width algebraic GIoU (corner-free).
//   Identity (general, incl. containment):
//     overlap = (h1+h2) - max(|c1-c2|, |h1-h2|)
//     enclose = (h1+h2) + max(|c1-c2|, |h1-h2|)
//   (from min(p,q) = ((p+q)-|p-q|)/2 and |d+e|+|d-e| = 2 max(|d|,|e|)).
//   R11's overlap = (h1+h2)-|c1-c2| dropped the |h1-h2| term -> wrong
//   whenever one box contains the other on an axis (absmax 1.6e5).
//   Reuses L1's |dx|,|dy|,|dw|,|dh|; corners never materialize.
//   Row state: {cx, cy, hw, hh, area} = 5 regs/row.
// ---------------------------------------------------------------------------
#define RT 2        // rows per thread (= rows per wave)
#define RTILE 8     // rows per block
#define NK 25       // 25 x 64 targets = 1600

__global__ __launch_bounds__(256)
void k_cost(const float* __restrict__ logits,
            const float* __restrict__ boxes,       // [BQ,4] cxcywh
            const int* __restrict__ tids,          // [TT] int32
            const float* __restrict__ tbox,        // [TT,4] cxcywh
            float* __restrict__ out) {
    __shared__ float pexp[RTILE][NCP];             // 3072 B

    const int row0 = blockIdx.x * RTILE;

    // ---- stage unnormalized exp(logit) via float2; pad cols 92..95 = 0 ----
    {
        int idx = threadIdx.x * 2;
        int r = idx / NCP, c = idx - r * NCP;
        float2 v = make_float2(0.0f, 0.0f);
        if (c < NC) {
            float2 lv = *(const float2*)&logits[(row0 + r) * NC + c];
            v.x = __expf(lv.x); v.y = __expf(lv.y);
        }
        *(float2*)&pexp[r][c] = v;
        if (threadIdx.x < 128) {
            int idx2 = 512 + threadIdx.x * 2;
            int r2 = idx2 / NCP, c2 = idx2 - r2 * NCP;
            float2 v2 = make_float2(0.0f, 0.0f);
            if (c2 < NC) {
                float2 lv = *(const float2*)&logits[(row0 + r2) * NC + c2];
                v2.x = __expf(lv.x); v2.y = __expf(lv.y);
            }
            *(float2*)&pexp[r2][c2] = v2;
        }
    }
    __syncthreads();

    // ---- normalize LDS probs in place (stride-3 cols, conflict-free) ----
    {
        const int r  = threadIdx.x >> 5;           // 0..7
        const int ls = threadIdx.x & 31;           // 0..31
        float a = pexp[r][ls * 3];
        float b = pexp[r][ls * 3 + 1];
        float d = pexp[r][ls * 3 + 2];
        float s = a + b + d;
        s += __shfl_xor(s, 1);
        s += __shfl_xor(s, 2);
        s += __shfl_xor(s, 4);
        s += __shfl_xor(s, 8);
        s += __shfl_xor(s, 16);
        float rinv = __builtin_amdgcn_rcpf(s);
        pexp[r][ls * 3]     = a * rinv;
        pexp[r][ls * 3 + 1] = b * rinv;
        pexp[r][ls * 3 + 2] = d * rinv;
    }

    const int tl   = threadIdx.x & 63;
    const int rg   = threadIdx.x >> 6;
    const int rloc = rg * RT;
    const int rbase = row0 + rloc;

    // ---- register-blocked row box data: center + HALF-widths + area ----
    float rcx[RT], rcy[RT], rhw[RT], rhh[RT], rar[RT];
    #pragma unroll
    for (int j = 0; j < RT; ++j) {
        float4 bb = ((const float4*)boxes)[rbase + j];
        rcx[j] = bb.x; rcy[j] = bb.y;
        rhw[j] = 0.5f * bb.z; rhh[j] = 0.5f * bb.w;
        rar[j] = bb.z * bb.w;
    }
    __syncthreads();

    // ---- main loop: 25 x 64 targets, prefetch, plain stores ----
    float* o0 = out + rbase * TT + tl;
    float4 tb = ((const float4*)tbox)[tl];
    int    id = tids[tl];
    #pragma unroll 5
    for (int k = 0; k < NK; ++k) {
        float4 tbn; int idn;
        if (k + 1 < NK) {
            tbn = ((const float4*)tbox)[(k + 1) * 64 + tl];
            idn = tids[(k + 1) * 64 + tl];
        }
        float thw = 0.5f * tb.z, thh = 0.5f * tb.w;
        float tar = tb.z * tb.w;
        #pragma unroll
        for (int j = 0; j < RT; ++j) {
            // center / half-width diffs (abs folds as VOP3 input modifier)
            float dx = rcx[j] - tb.x;
            float dy = rcy[j] - tb.y;
            float dw = rhw[j] - thw;               // half of (rw - tw)
            float dh = rhh[j] - thh;
            // L1 = |dx|+|dy|+2(|dw|+|dh|)
            float a1 = fabsf(dx) + fabsf(dy);
            float a2 = fabsf(dw) + fabsf(dh);
            float l1 = fmaf(2.0f, a2, a1);
            // general interval identity:
            //   overlap = s - max(|d|,|dh|),  enclose = s + max(|d|,|dh|)
            float mx = fmaxf(fabsf(dx), fabsf(dw));
            float my = fmaxf(fabsf(dy), fabsf(dh));
            float sx = rhw[j] + thw;
            float sy = rhh[j] + thh;
            float iwu = sx - mx;
            float ihu = sy - my;
            float ew  = sx + mx;
            float eh  = sy + my;
            float inter = fmaxf(iwu, 0.0f) * fmaxf(ihu, 0.0f);
            float uni = (rar[j] + tar) - inter;
            float ea = ew * eh;
            // giou = (ea*(inter-uni) + uni^2) / (uni*ea), single rcp
            float num = fmaf(ea, inter - uni, uni * uni);
            float rden = __builtin_amdgcn_rcpf(uni * ea);
            // C = 5*l1 - p - 2*giou
            float p = pexp[rloc + j][id];
            float c = fmaf(5.0f, l1, -p);
            c = fmaf(-2.0f * num, rden, c);
            o0[j * TT + k * 64] = c;
        }
        tb = tbn; id = idn;
    }
}

// ---------------------------------------------------------------------------
extern "C" void kernel_launch(void* const* d_in, const int* in_sizes, int n_in,
                              void* d_out, int out_size, void* d_ws, size_t ws_size,
                              hipStream_t stream) {
    const float* logits = (const float*)d_in[0];   // [16,900,92] f32
    const float* boxes  = (const float*)d_in[1];   // [16,900,4]  f32
    const int*   tids   = (const int*)  d_in[2];   // [1600] int32
    const float* tbox   = (const float*)d_in[3];   // [1600,4] f32
    float* out = (float*)d_out;

    k_cost<<<dim3(BQ / RTILE, 1), 256, 0, stream>>>(
        logits, boxes, tids, tbox, out);
}